// Round 1
// baseline (815.725 us; speedup 1.0000x reference)
//
#include <hip/hip_runtime.h>
#include <cstdint>
#include <cstddef>

// ---------------------------------------------------------------------------
// CrossDynamicConv — dead-code-eliminated implementation.
// Outputs: (f, p_in, p_out). Only iteration i=3's u_in/u_out reach f; all
// shift (W_sh/W_sw) computations and loop iterations 0..2 are dead.
//
// R1 changes vs 910.7 µs baseline:
//  - k_dyn: inputs pre-converted to bf16 (k_wdynt transposes W_dyn ->
//    [32768][256] bf16; k_abf converts pf). Hot loop staging is now pure
//    uint4 copies — no f2bfu / scalar loads in the K-loop. Bit-identical
//    numerics (same RNE conversion, applied once instead of per-tile).
//  - k_gates: needed 640 weight columns compacted once (k_wgc) into
//    Wc[256][640] so the gate GEMV loads are coalesced (was 16B-strided).
//  - workspace re-laid-out with lifetime aliasing: 51.5 MB (< old 62.3 MB).
// ---------------------------------------------------------------------------

typedef __attribute__((ext_vector_type(8))) short bf16x8;
typedef __attribute__((ext_vector_type(4))) float floatx4;

#define NPROP 1024
#define CIN   256
#define FEAT  64
#define HWs   49
#define OUTC  256
#define CF    16384      // CIN*FEAT
#define KDYN  32768      // CIN*FEAT + FEAT*OUTC
#define KFC   12544      // HWs*OUTC

__device__ __forceinline__ unsigned short f2bfu(float x) {
  union { float f; uint32_t u; } v; v.f = x;
  uint32_t r = v.u + 0x7fffu + ((v.u >> 16) & 1u);   // RNE
  return (unsigned short)(r >> 16);
}

// ---------------------------------------------------------------------------
// W_dyn fp32 [256][32768] -> bf16 transposed [32768][256]
// ---------------------------------------------------------------------------
__global__ __launch_bounds__(256) void k_wdynt(
    const float* __restrict__ W, unsigned short* __restrict__ Bt)
{
  __shared__ float tile[64][65];
  const int k0 = blockIdx.x*64;   // K: 256/64 = 4
  const int o0 = blockIdx.y*64;   // N: 32768/64 = 512
  const int t = threadIdx.x;
  const int a = t & 63, b = t >> 6;
  #pragma unroll
  for (int r = 0; r < 16; ++r) {
    const int k = b + (r << 2);
    tile[k][a] = W[(size_t)(k0 + k)*KDYN + o0 + a];
  }
  __syncthreads();
  #pragma unroll
  for (int r = 0; r < 16; ++r) {
    const int o = b + (r << 2);
    Bt[(size_t)(o0 + o)*CIN + k0 + a] = f2bfu(tile[a][o]);
  }
}

// ---------------------------------------------------------------------------
// pf fp32 [1024][256] -> bf16 [1024][256]
// ---------------------------------------------------------------------------
__global__ __launch_bounds__(256) void k_abf(
    const float* __restrict__ A, unsigned short* __restrict__ Ab)
{
  const int i = (blockIdx.x*256 + threadIdx.x)*4;
  const float4 v = *(const float4*)(A + i);
  uint2 pk;
  pk.x = (uint32_t)f2bfu(v.x) | ((uint32_t)f2bfu(v.y) << 16);
  pk.y = (uint32_t)f2bfu(v.z) | ((uint32_t)f2bfu(v.w) << 16);
  *(uint2*)(Ab + i) = pk;
}

// ---------------------------------------------------------------------------
// Compact the 640 needed gate-weight columns (l=3 slice) into Wc[c][u],
// u-major contiguous so k_gates' loads coalesce across lanes.
// u<64: WM1 col u*4+3 | u<320: WM2 col (u-64)*4+3 | u<384: WS1 | else WS2
// ---------------------------------------------------------------------------
__global__ __launch_bounds__(256) void k_wgc(
    const float* __restrict__ WM1, const float* __restrict__ WM2,
    const float* __restrict__ WS1, const float* __restrict__ WS2,
    float* __restrict__ Wc)
{
  const int c = blockIdx.x;
  for (int u = threadIdx.x; u < 640; u += 256) {
    const float* W; int col, stride;
    if (u < 64)       { W = WM1; col = u*4 + 3;        stride = 256;  }
    else if (u < 320) { W = WM2; col = (u-64)*4 + 3;   stride = 1024; }
    else if (u < 384) { W = WS1; col = (u-320)*4 + 3;  stride = 256;  }
    else              { W = WS2; col = (u-384)*4 + 3;  stride = 1024; }
    Wc[(size_t)c*640 + u] = W[(size_t)c*stride + col];
  }
}

// ---------------------------------------------------------------------------
// Gates: m1/m2/s1/s2 for l=3 only, from compacted Wc (coalesced loads).
// ---------------------------------------------------------------------------
__global__ __launch_bounds__(256) void k_gates(
    const float* __restrict__ pf, const float* __restrict__ Wc,
    const float* __restrict__ bM1, const float* __restrict__ bM2,
    const float* __restrict__ bS1, const float* __restrict__ bS2,
    float* __restrict__ gm1, float* __restrict__ gm2,
    float* __restrict__ gs1, float* __restrict__ gs2)
{
  const int n = blockIdx.x;
  const int t = threadIdx.x;
  __shared__ float p[CIN];
  p[t] = pf[n*CIN + t];
  __syncthreads();
  for (int u = t; u < 640; u += 256) {
    float acc; float* dst; int idx;
    if (u < 64)       { acc = bM1[u*4 + 3];        dst = gm1 + n*FEAT; idx = u;     }
    else if (u < 320) { acc = bM2[(u-64)*4 + 3];   dst = gm2 + n*CIN;  idx = u-64;  }
    else if (u < 384) { acc = bS1[(u-320)*4 + 3];  dst = gs1 + n*FEAT; idx = u-320; }
    else              { acc = bS2[(u-384)*4 + 3];  dst = gs2 + n*OUTC; idx = u-384; }
    #pragma unroll 8
    for (int c = 0; c < CIN; ++c) acc += p[c] * Wc[(size_t)c*640 + u];
    dst[idx] = 1.0f / (1.0f + __expf(-acc));
  }
}

// ---------------------------------------------------------------------------
// Dyn GEMM: params = pf @ W_dyn + b_dyn, bf16 MFMA 16x16x32.
// M=1024, K=256, N=32768. Block tile 128x128, BK=64, 4 waves each 64x64.
// Inputs pre-converted bf16: Abf [1024][256], Bt [32768][256] (K-contig).
// Writes p_in / p_out directly into d_out regions.
// ---------------------------------------------------------------------------
__global__ __launch_bounds__(256) void k_dyn(
    const unsigned short* __restrict__ Abf, const unsigned short* __restrict__ Bt,
    const float* __restrict__ bias, float* __restrict__ out)
{
  const int bn = blockIdx.x;   // 0..255
  const int bm = blockIdx.y;   // 0..7
  __shared__ short As[128*72]; // [row][k], pad 64->72
  __shared__ short Bs[128*72]; // [col][k]
  const int t = threadIdx.x;
  const int wave = t >> 6, lane = t & 63;
  const int q = lane >> 4, l15 = lane & 15;
  const int wm = wave >> 1, wn = wave & 1;
  floatx4 acc[4][4];
  #pragma unroll
  for (int mt=0;mt<4;++mt)
    #pragma unroll
    for (int nt=0;nt<4;++nt)
      #pragma unroll
      for (int r=0;r<4;++r) acc[mt][nt][r] = 0.f;

  const int r0 = t >> 3;        // 0..31
  const int kc = (t & 7) * 8;   // 0,8,..,56 (bf16 elems)

  for (int ks = 0; ks < 4; ++ks) {
    #pragma unroll
    for (int p = 0; p < 4; ++p) {
      const int row = r0 + p*32;
      *(uint4*)&As[row*72 + kc] =
          *(const uint4*)(Abf + (size_t)(bm*128 + row)*CIN + ks*64 + kc);
      *(uint4*)&Bs[row*72 + kc] =
          *(const uint4*)(Bt  + (size_t)(bn*128 + row)*CIN + ks*64 + kc);
    }
    __syncthreads();
    #pragma unroll
    for (int kk = 0; kk < 2; ++kk) {
      bf16x8 af[4], bfr[4];
      #pragma unroll
      for (int mt = 0; mt < 4; ++mt)
        af[mt] = *(const bf16x8*)&As[(wm*64 + mt*16 + l15)*72 + kk*32 + q*8];
      #pragma unroll
      for (int nt = 0; nt < 4; ++nt)
        bfr[nt] = *(const bf16x8*)&Bs[(wn*64 + nt*16 + l15)*72 + kk*32 + q*8];
      #pragma unroll
      for (int mt = 0; mt < 4; ++mt)
        #pragma unroll
        for (int nt = 0; nt < 4; ++nt)
          acc[mt][nt] = __builtin_amdgcn_mfma_f32_16x16x32_bf16(af[mt], bfr[nt], acc[mt][nt], 0, 0, 0);
    }
    __syncthreads();
  }
  #pragma unroll
  for (int nt = 0; nt < 4; ++nt) {
    const int j = bn*128 + wn*64 + nt*16 + l15;
    const float bv = bias[j];
    float* base; int jj;
    if (j < CF) { base = out + 262144;            jj = j;      }
    else        { base = out + 262144 + 16777216; jj = j - CF; }
    #pragma unroll
    for (int mt = 0; mt < 4; ++mt) {
      const int m0 = bm*128 + wm*64 + mt*16 + q*4;
      #pragma unroll
      for (int r = 0; r < 4; ++r)
        base[(size_t)(m0 + r)*CF + jj] = acc[mt][nt][r] + bv;
    }
  }
}

// ---------------------------------------------------------------------------
// k_in: per-n  t = relu(ln(x @ u_in, g_in, b_in)), u_in built on the fly.
// x[h][c] = input_feature[n][c][h]. LN over F=64 == lane dim.
// K chunked by 128 to stay under 64KB LDS.
// ---------------------------------------------------------------------------
__global__ __launch_bounds__(256) void k_in(
    const float* __restrict__ infeat, const float* __restrict__ pre3,
    const float* __restrict__ pin,
    const float* __restrict__ gm1, const float* __restrict__ gm2,
    const float* __restrict__ gin, const float* __restrict__ bin,
    float* __restrict__ tbuf)
{
  const int n = blockIdx.x;
  const int t = threadIdx.x;
  const int wave = t >> 6, lane = t & 63;
  __shared__ float us[128*64];        // u_in chunk [c_local][f]
  __shared__ float xs[128*52 + 16];   // x chunk [c_local][h], row pad 49->52
  __shared__ float m1s[64];
  __shared__ float m2s[256];
  if (t < 64) m1s[t] = gm1[n*64 + t];
  m2s[t] = gm2[n*256 + t];

  float acc[16];
  #pragma unroll
  for (int i = 0; i < 16; ++i) acc[i] = 0.f;

  for (int cc = 0; cc < 2; ++cc) {
    __syncthreads();
    for (int i = t; i < 128*49; i += 256) {
      const int c = i / 49, h = i - c*49;
      xs[c*52 + h] = infeat[(size_t)n*12544 + (size_t)(cc*128 + c)*49 + h];
    }
    for (int i = t*4; i < 8192; i += 1024) {
      const int gi = cc*8192 + i;
      const float4 pr = *(const float4*)(pre3 + (size_t)n*16384 + gi);
      const float4 pp = *(const float4*)(pin  + (size_t)n*16384 + gi);
      const int c = gi >> 6, f0 = gi & 63;
      const float m2v = m2s[c];
      float4 w;
      { const float m1v = m1s[f0+0]; const float ui = m1v*pr.x + (1.f-m1v)*pp.x; w.x = m2v*ui + (1.f-m2v)*pp.x; }
      { const float m1v = m1s[f0+1]; const float ui = m1v*pr.y + (1.f-m1v)*pp.y; w.y = m2v*ui + (1.f-m2v)*pp.y; }
      { const float m1v = m1s[f0+2]; const float ui = m1v*pr.z + (1.f-m1v)*pp.z; w.z = m2v*ui + (1.f-m2v)*pp.z; }
      { const float m1v = m1s[f0+3]; const float ui = m1v*pr.w + (1.f-m1v)*pp.w; w.w = m2v*ui + (1.f-m2v)*pp.w; }
      *(float4*)&us[i] = w;
    }
    __syncthreads();
    #pragma unroll
    for (int p = 0; p < 2; ++p) {
      const int hbase = p*32 + wave*8;
      float* accp = &acc[p*8];
      for (int c = 0; c < 128; ++c) {
        const float uv = us[c*64 + lane];
        const float4 xa = *(const float4*)&xs[c*52 + hbase];
        const float4 xb = *(const float4*)&xs[c*52 + hbase + 4];
        accp[0] += uv*xa.x; accp[1] += uv*xa.y; accp[2] += uv*xa.z; accp[3] += uv*xa.w;
        accp[4] += uv*xb.x; accp[5] += uv*xb.y; accp[6] += uv*xb.z; accp[7] += uv*xb.w;
      }
    }
  }
  const float gv = gin[lane], bv = bin[lane];
  #pragma unroll
  for (int p = 0; p < 2; ++p) {
    const int hbase = p*32 + wave*8;
    #pragma unroll
    for (int j = 0; j < 8; ++j) {
      const int h = hbase + j;
      if (h >= 49) break;                 // wave-uniform
      const float v = acc[p*8+j];
      float s1 = v, s2 = v*v;
      #pragma unroll
      for (int off = 32; off > 0; off >>= 1) {
        s1 += __shfl_xor(s1, off);
        s2 += __shfl_xor(s2, off);
      }
      const float mean = s1 * (1.f/64.f);
      const float var  = s2 * (1.f/64.f) - mean*mean;
      const float rs   = rsqrtf(var + 1e-5f);
      const float o    = (v - mean)*rs*gv + bv;
      tbuf[(size_t)(n*49 + h)*64 + lane] = fmaxf(o, 0.f);
    }
  }
}

// ---------------------------------------------------------------------------
// k_out: per-n  f = relu(ln(t @ u_out, g_out, b_out)), u_out built on the fly.
// LN over OUT=256 = 4 register chunks x 64 lanes. Output stored as bf16 for fc.
// F chunked by 32 to stay under 64KB LDS.
// ---------------------------------------------------------------------------
__global__ __launch_bounds__(256) void k_out(
    const float* __restrict__ tbuf, const float* __restrict__ pre3,
    const float* __restrict__ pout,
    const float* __restrict__ gs1, const float* __restrict__ gs2,
    const float* __restrict__ gout, const float* __restrict__ bout,
    unsigned short* __restrict__ fbuf)
{
  const int n = blockIdx.x;
  const int t = threadIdx.x;
  const int wave = t >> 6, lane = t & 63;
  __shared__ float u2s[32*256];       // u_out chunk [f_local][o]
  __shared__ float ts2[64*52 + 16];   // t transposed [f][h], row pad 49->52
  __shared__ float s1s[64];
  __shared__ float s2s[256];
  if (t < 64) s1s[t] = gs1[n*64 + t];
  s2s[t] = gs2[n*256 + t];
  for (int i = t; i < 3136; i += 256) {
    const int h = i >> 6, f = i & 63;
    ts2[f*52 + h] = tbuf[(size_t)n*3136 + i];
  }

  float acc[2][8][4];
  #pragma unroll
  for (int p=0;p<2;++p)
    #pragma unroll
    for (int j=0;j<8;++j)
      #pragma unroll
      for (int k=0;k<4;++k) acc[p][j][k] = 0.f;

  for (int fc_ = 0; fc_ < 2; ++fc_) {
    __syncthreads();
    for (int i = t*4; i < 8192; i += 1024) {
      const int gi = fc_*8192 + i;
      const float4 pr = *(const float4*)(pre3 + (size_t)n*16384 + gi);
      const float4 pp = *(const float4*)(pout + (size_t)n*16384 + gi);
      const int f = gi >> 8, o0 = gi & 255;
      const float s1v = s1s[f];
      float4 w;
      { const float s2v = s2s[o0+0]; const float uo = s1v*pr.x + (1.f-s1v)*pp.x; w.x = s2v*uo + (1.f-s2v)*pp.x; }
      { const float s2v = s2s[o0+1]; const float uo = s1v*pr.y + (1.f-s1v)*pp.y; w.y = s2v*uo + (1.f-s2v)*pp.y; }
      { const float s2v = s2s[o0+2]; const float uo = s1v*pr.z + (1.f-s1v)*pp.z; w.z = s2v*uo + (1.f-s2v)*pp.z; }
      { const float s2v = s2s[o0+3]; const float uo = s1v*pr.w + (1.f-s1v)*pp.w; w.w = s2v*uo + (1.f-s2v)*pp.w; }
      *(float4*)&u2s[i] = w;
    }
    __syncthreads();
    #pragma unroll
    for (int p = 0; p < 2; ++p) {
      const int hbase = (p*4 + wave)*8;
      for (int fl = 0; fl < 32; ++fl) {
        const float u0 = u2s[fl*256 + lane];
        const float u1 = u2s[fl*256 + lane + 64];
        const float u2v= u2s[fl*256 + lane + 128];
        const float u3 = u2s[fl*256 + lane + 192];
        const int f = fc_*32 + fl;
        const float4 ta = *(const float4*)&ts2[f*52 + hbase];
        const float4 tb = *(const float4*)&ts2[f*52 + hbase + 4];
        const float tv[8] = {ta.x,ta.y,ta.z,ta.w,tb.x,tb.y,tb.z,tb.w};
        #pragma unroll
        for (int j = 0; j < 8; ++j) {
          acc[p][j][0] += tv[j]*u0;
          acc[p][j][1] += tv[j]*u1;
          acc[p][j][2] += tv[j]*u2v;
          acc[p][j][3] += tv[j]*u3;
        }
      }
    }
  }
  const float go0=gout[lane], go1=gout[lane+64], go2=gout[lane+128], go3=gout[lane+192];
  const float bo0=bout[lane], bo1=bout[lane+64], bo2=bout[lane+128], bo3=bout[lane+192];
  #pragma unroll
  for (int p = 0; p < 2; ++p) {
    const int hbase = (p*4 + wave)*8;
    #pragma unroll
    for (int j = 0; j < 8; ++j) {
      const int h = hbase + j;
      if (h >= 49) break;                 // wave-uniform
      const float v0 = acc[p][j][0], v1 = acc[p][j][1], v2 = acc[p][j][2], v3 = acc[p][j][3];
      float s1 = v0+v1+v2+v3;
      float s2 = v0*v0+v1*v1+v2*v2+v3*v3;
      #pragma unroll
      for (int off = 32; off > 0; off >>= 1) {
        s1 += __shfl_xor(s1, off);
        s2 += __shfl_xor(s2, off);
      }
      const float mean = s1 * (1.f/256.f);
      const float var  = s2 * (1.f/256.f) - mean*mean;
      const float rs   = rsqrtf(var + 1e-5f);
      unsigned short* dst = fbuf + (size_t)(n*49 + h)*256;
      dst[lane      ] = f2bfu(fmaxf((v0-mean)*rs*go0 + bo0, 0.f));
      dst[lane + 64 ] = f2bfu(fmaxf((v1-mean)*rs*go1 + bo1, 0.f));
      dst[lane + 128] = f2bfu(fmaxf((v2-mean)*rs*go2 + bo2, 0.f));
      dst[lane + 192] = f2bfu(fmaxf((v3-mean)*rs*go3 + bo3, 0.f));
    }
  }
}

// ---------------------------------------------------------------------------
// W_fc fp32 [12544][256] -> bf16 transposed [256][12544]
// ---------------------------------------------------------------------------
__global__ __launch_bounds__(256) void k_wfct(
    const float* __restrict__ W, unsigned short* __restrict__ Wt)
{
  __shared__ float tile[64][65];
  const int k0 = blockIdx.x*64, o0 = blockIdx.y*64;
  const int t = threadIdx.x;
  const int a = t & 63, b = t >> 6;
  #pragma unroll
  for (int r = 0; r < 16; ++r) {
    const int k = b + (r << 2);
    tile[k][a] = W[(size_t)(k0 + k)*256 + o0 + a];
  }
  __syncthreads();
  #pragma unroll
  for (int r = 0; r < 16; ++r) {
    const int o = b + (r << 2);
    Wt[(size_t)(o0 + o)*KFC + k0 + a] = f2bfu(tile[a][o]);
  }
}

// ---------------------------------------------------------------------------
// fc GEMM: partial[bk] = f_bf16[64 rows] @ Wfc_t chunk. bf16 MFMA.
// Grid (16 bm, 2 bn, 14 bk); chunk K = 896 = 14 * 64.
// ---------------------------------------------------------------------------
__global__ __launch_bounds__(256) void k_fc(
    const unsigned short* __restrict__ Abf, const unsigned short* __restrict__ Bbf,
    float* __restrict__ part)
{
  const int bm = blockIdx.x, bn = blockIdx.y, bk = blockIdx.z;
  __shared__ short As[64*72];
  __shared__ short Bs[128*72];
  const int t = threadIdx.x;
  const int wave = t >> 6, lane = t & 63;
  const int q = lane >> 4, l15 = lane & 15;
  floatx4 acc[4][2];
  #pragma unroll
  for (int mt=0;mt<4;++mt)
    #pragma unroll
    for (int nt=0;nt<2;++nt)
      #pragma unroll
      for (int r=0;r<4;++r) acc[mt][nt][r] = 0.f;

  for (int ks = 0; ks < 14; ++ks) {
    const int k0 = bk*896 + ks*64;
    {
      int row = t >> 3; const int kc = (t & 7) * 8;
      #pragma unroll
      for (int p2 = 0; p2 < 2; ++p2, row += 32) {
        const uint4 v = *(const uint4*)(Abf + (size_t)(bm*64 + row)*KFC + k0 + kc);
        *(uint4*)&As[row*72 + kc] = v;
      }
    }
    {
      int col = t >> 3; const int kc = (t & 7) * 8;
      #pragma unroll
      for (int p2 = 0; p2 < 4; ++p2, col += 32) {
        const uint4 v = *(const uint4*)(Bbf + (size_t)(bn*128 + col)*KFC + k0 + kc);
        *(uint4*)&Bs[col*72 + kc] = v;
      }
    }
    __syncthreads();
    #pragma unroll
    for (int kk = 0; kk < 2; ++kk) {
      bf16x8 af[4], bfr[2];
      #pragma unroll
      for (int mt = 0; mt < 4; ++mt)
        af[mt] = *(const bf16x8*)&As[(mt*16 + l15)*72 + kk*32 + q*8];
      #pragma unroll
      for (int nt = 0; nt < 2; ++nt)
        bfr[nt] = *(const bf16x8*)&Bs[(wave*32 + nt*16 + l15)*72 + kk*32 + q*8];
      #pragma unroll
      for (int mt = 0; mt < 4; ++mt)
        #pragma unroll
        for (int nt = 0; nt < 2; ++nt)
          acc[mt][nt] = __builtin_amdgcn_mfma_f32_16x16x32_bf16(af[mt], bfr[nt], acc[mt][nt], 0, 0, 0);
    }
    __syncthreads();
  }
  float* dst = part + (size_t)bk*NPROP*OUTC;
  #pragma unroll
  for (int mt = 0; mt < 4; ++mt)
    #pragma unroll
    for (int nt = 0; nt < 2; ++nt) {
      const int o  = bn*128 + wave*32 + nt*16 + l15;
      const int m0 = bm*64 + mt*16 + q*4;
      #pragma unroll
      for (int r = 0; r < 4; ++r)
        dst[(size_t)(m0 + r)*OUTC + o] = acc[mt][nt][r];
    }
}

// ---------------------------------------------------------------------------
// fc reduce: sum 14 partials + b_fc, LN(g_fcn,b_fcn), relu -> out[0:262144]
// ---------------------------------------------------------------------------
__global__ __launch_bounds__(256) void k_fcred(
    const float* __restrict__ part, const float* __restrict__ bfc,
    const float* __restrict__ gn, const float* __restrict__ bnm,
    float* __restrict__ out0)
{
  const int n = blockIdx.x, t = threadIdx.x;
  float acc = bfc[t];
  #pragma unroll
  for (int s = 0; s < 14; ++s) acc += part[(size_t)s*NPROP*OUTC + n*256 + t];
  __shared__ float red[8];
  float s1 = acc, s2 = acc*acc;
  #pragma unroll
  for (int off = 32; off > 0; off >>= 1) {
    s1 += __shfl_xor(s1, off);
    s2 += __shfl_xor(s2, off);
  }
  const int wave = t >> 6, lane = t & 63;
  if (lane == 0) { red[wave] = s1; red[4+wave] = s2; }
  __syncthreads();
  const float S1 = red[0]+red[1]+red[2]+red[3];
  const float S2 = red[4]+red[5]+red[6]+red[7];
  const float mean = S1 * (1.f/256.f);
  const float var  = S2 * (1.f/256.f) - mean*mean;
  const float rs   = rsqrtf(var + 1e-5f);
  const float v = (acc - mean)*rs*gn[t] + bnm[t];
  out0[n*256 + t] = fmaxf(v, 0.f);
}

// ---------------------------------------------------------------------------
extern "C" void kernel_launch(void* const* d_in, const int* in_sizes, int n_in,
                              void* d_out, int out_size, void* d_ws, size_t ws_size,
                              hipStream_t stream)
{
  const float* pf    = (const float*)d_in[0];
  const float* infe  = (const float*)d_in[1];
  const float* preI  = (const float*)d_in[2];
  const float* preO  = (const float*)d_in[3];
  const float* Wdyn  = (const float*)d_in[4];
  const float* bdyn  = (const float*)d_in[5];
  const float* g_in  = (const float*)d_in[6];
  const float* b_in  = (const float*)d_in[7];
  const float* g_out = (const float*)d_in[8];
  const float* b_out = (const float*)d_in[9];
  const float* Wfc   = (const float*)d_in[10];
  const float* bfc   = (const float*)d_in[11];
  const float* gfcn  = (const float*)d_in[12];
  const float* bfcn  = (const float*)d_in[13];
  const float* WM1   = (const float*)d_in[14];
  const float* bM1   = (const float*)d_in[15];
  const float* WM2   = (const float*)d_in[16];
  const float* bM2   = (const float*)d_in[17];
  const float* WS1   = (const float*)d_in[18];
  const float* bS1   = (const float*)d_in[19];
  const float* WS2   = (const float*)d_in[20];
  const float* bS2   = (const float*)d_in[21];

  // ws layout (bytes), lifetime-aliased:
  //      0 gm1   (262144)
  // 262144 gm2   (1048576)
  // 1310720 gs1  (262144)
  // 1572864 gs2  (1048576)
  // 2621440 shared region (16777216):
  //         wdynt bf16 [live k_wdynt..k_dyn]
  //         tbuf fp32  [live k_in..k_out]
  //         part fp32  [live k_fc..k_fcred]
  // 19398656 fbuf bf16 (25690112) [live k_out..k_fc]
  //          abf bf16 (524288)  aliases fbuf head [live k_abf..k_dyn]
  //          wgc fp32 (655360)  at fbuf+524288    [live k_wgc..k_gates]
  // 45088768 wfct bf16 (6422528) [live k_wfct..k_fc]
  // total 51511296 B
  char* wsb = (char*)d_ws;
  float* gm1  = (float*)(wsb + 0);
  float* gm2  = (float*)(wsb + 262144);
  float* gs1  = (float*)(wsb + 1310720);
  float* gs2  = (float*)(wsb + 1572864);
  unsigned short* wdynt = (unsigned short*)(wsb + 2621440);
  float* tbuf = (float*)(wsb + 2621440);
  float* part = (float*)(wsb + 2621440);
  unsigned short* fbuf = (unsigned short*)(wsb + 19398656);
  unsigned short* abf  = (unsigned short*)(wsb + 19398656);
  float* wgc           = (float*)(wsb + 19398656 + 524288);
  unsigned short* wfct = (unsigned short*)(wsb + 45088768);

  const float* pre_in3  = preI + (size_t)3*NPROP*CIN*FEAT;
  const float* pre_out3 = preO + (size_t)3*NPROP*FEAT*OUTC;
  const float* p_in  = (const float*)d_out + 262144;
  const float* p_out = (const float*)d_out + 262144 + 16777216;
  float* out0 = (float*)d_out;

  k_wdynt<<<dim3(4, 512), 256, 0, stream>>>(Wdyn, wdynt);
  k_abf  <<<dim3(256),    256, 0, stream>>>(pf, abf);
  k_wgc  <<<dim3(256),    256, 0, stream>>>(WM1, WM2, WS1, WS2, wgc);
  k_wfct <<<dim3(196, 4), 256, 0, stream>>>(Wfc, wfct);
  k_gates<<<dim3(1024),   256, 0, stream>>>(pf, wgc, bM1, bM2, bS1, bS2,
                                            gm1, gm2, gs1, gs2);
  k_dyn  <<<dim3(256, 8), 256, 0, stream>>>(abf, wdynt, bdyn, (float*)d_out);
  k_in   <<<dim3(1024),   256, 0, stream>>>(infe, pre_in3, p_in, gm1, gm2, g_in, b_in, tbuf);
  k_out  <<<dim3(1024),   256, 0, stream>>>(tbuf, pre_out3, p_out, gs1, gs2, g_out, b_out, fbuf);
  k_fc   <<<dim3(16, 2, 14), 256, 0, stream>>>(fbuf, wfct, part);
  k_fcred<<<dim3(1024),   256, 0, stream>>>(part, bfc, gfcn, bfcn, out0);
}

// Round 2
// 781.092 us; speedup vs baseline: 1.0443x; 1.0443x over previous
//
#include <hip/hip_runtime.h>
#include <cstdint>
#include <cstddef>

// ---------------------------------------------------------------------------
// CrossDynamicConv — dead-code-eliminated implementation.
// Outputs: (f, p_in, p_out). Only iteration i=3's u_in/u_out reach f; all
// shift (W_sh/W_sw) computations and loop iterations 0..2 are dead.
//
// R2 changes vs 815.7 µs:
//  - 10 kernels -> 6: k_prep merges {wdynt, wfct, abf, gate-col pack};
//    k_inout fuses k_in+k_out (t stays in LDS, tbuf round-trip eliminated).
//  - k_gates -> k_gatesM: bf16 MFMA GEMM [1024,256]@[256,640] + fused
//    sigmoid epilogue (40 blocks vs 1024 blocks re-reading 655 KB each).
//    Gate bf16 error ~5e-4 is damped by sigmoid and the downstream LN.
// ---------------------------------------------------------------------------

typedef __attribute__((ext_vector_type(8))) short bf16x8;
typedef __attribute__((ext_vector_type(4))) float floatx4;

#define NPROP 1024
#define CIN   256
#define FEAT  64
#define HWs   49
#define OUTC  256
#define CF    16384      // CIN*FEAT
#define KDYN  32768      // CIN*FEAT + FEAT*OUTC
#define KFC   12544      // HWs*OUTC

__device__ __forceinline__ unsigned short f2bfu(float x) {
  union { float f; uint32_t u; } v; v.f = x;
  uint32_t r = v.u + 0x7fffu + ((v.u >> 16) & 1u);   // RNE
  return (unsigned short)(r >> 16);
}

// ---------------------------------------------------------------------------
// k_prep: all input preprocessing in one launch.
//  blocks [0,2048)    : W_dyn fp32 [256][32768] -> bf16 [32768][256]
//  blocks [2048,2832) : W_fc  fp32 [12544][256] -> bf16 [256][12544]
//  blocks [2832,3088) : pf fp32 -> bf16 [1024][256]
//  blocks [3088,3728) : gate cols (l=3) -> Wcb bf16 [640][256] + bgc[640]
// ---------------------------------------------------------------------------
__global__ __launch_bounds__(256) void k_prep(
    const float* __restrict__ Wdyn, unsigned short* __restrict__ wdynt,
    const float* __restrict__ Wfc,  unsigned short* __restrict__ wfct,
    const float* __restrict__ pf,   unsigned short* __restrict__ abf,
    const float* __restrict__ WM1, const float* __restrict__ WM2,
    const float* __restrict__ WS1, const float* __restrict__ WS2,
    const float* __restrict__ bM1, const float* __restrict__ bM2,
    const float* __restrict__ bS1, const float* __restrict__ bS2,
    unsigned short* __restrict__ wgcb, float* __restrict__ bgc)
{
  __shared__ float tile[64][65];
  const int b = blockIdx.x;
  const int t = threadIdx.x;
  if (b < 2048) {
    const int k0 = (b & 3)*64, o0 = (b >> 2)*64;
    const int a = t & 63, w = t >> 6;
    #pragma unroll
    for (int r = 0; r < 16; ++r) {
      const int k = w + (r << 2);
      tile[k][a] = Wdyn[(size_t)(k0 + k)*KDYN + o0 + a];
    }
    __syncthreads();
    #pragma unroll
    for (int r = 0; r < 16; ++r) {
      const int o = w + (r << 2);
      wdynt[(size_t)(o0 + o)*CIN + k0 + a] = f2bfu(tile[a][o]);
    }
  } else if (b < 2832) {
    const int b2 = b - 2048;
    const int k0 = (b2 % 196)*64, o0 = (b2 / 196)*64;
    const int a = t & 63, w = t >> 6;
    #pragma unroll
    for (int r = 0; r < 16; ++r) {
      const int k = w + (r << 2);
      tile[k][a] = Wfc[(size_t)(k0 + k)*256 + o0 + a];
    }
    __syncthreads();
    #pragma unroll
    for (int r = 0; r < 16; ++r) {
      const int o = w + (r << 2);
      wfct[(size_t)(o0 + o)*KFC + k0 + a] = f2bfu(tile[a][o]);
    }
  } else if (b < 3088) {
    const int i = ((b - 2832)*256 + t)*4;
    const float4 v = *(const float4*)(pf + i);
    uint2 pk;
    pk.x = (uint32_t)f2bfu(v.x) | ((uint32_t)f2bfu(v.y) << 16);
    pk.y = (uint32_t)f2bfu(v.z) | ((uint32_t)f2bfu(v.w) << 16);
    *(uint2*)(abf + i) = pk;
  } else {
    const int u = b - 3088;       // 0..639
    const float* W; const float* bb; int col, stride;
    if (u < 64)       { W = WM1; bb = bM1; col = u*4 + 3;        stride = 256;  }
    else if (u < 320) { W = WM2; bb = bM2; col = (u-64)*4 + 3;   stride = 1024; }
    else if (u < 384) { W = WS1; bb = bS1; col = (u-320)*4 + 3;  stride = 256;  }
    else              { W = WS2; bb = bS2; col = (u-384)*4 + 3;  stride = 1024; }
    wgcb[(size_t)u*256 + t] = f2bfu(W[(size_t)t*stride + col]);
    if (t == 0) bgc[u] = bb[col];
  }
}

// ---------------------------------------------------------------------------
// k_gatesM: gates = sigmoid(pf @ Wc + bgc), bf16 MFMA.
// M=1024, K=256, N=640. Tile 128x128, grid (5,8). Scatter to gm1/gm2/gs1/gs2.
// ---------------------------------------------------------------------------
__global__ __launch_bounds__(256) void k_gatesM(
    const unsigned short* __restrict__ Abf, const unsigned short* __restrict__ Wcb,
    const float* __restrict__ bgc,
    float* __restrict__ gm1, float* __restrict__ gm2,
    float* __restrict__ gs1, float* __restrict__ gs2)
{
  const int bn = blockIdx.x;   // 0..4
  const int bm = blockIdx.y;   // 0..7
  __shared__ short As[128*72];
  __shared__ short Bs[128*72];
  const int t = threadIdx.x;
  const int wave = t >> 6, lane = t & 63;
  const int q = lane >> 4, l15 = lane & 15;
  const int wm = wave >> 1, wn = wave & 1;
  floatx4 acc[4][4];
  #pragma unroll
  for (int mt=0;mt<4;++mt)
    #pragma unroll
    for (int nt=0;nt<4;++nt)
      #pragma unroll
      for (int r=0;r<4;++r) acc[mt][nt][r] = 0.f;

  const int r0 = t >> 3;
  const int kc = (t & 7) * 8;

  for (int ks = 0; ks < 4; ++ks) {
    #pragma unroll
    for (int p = 0; p < 4; ++p) {
      const int row = r0 + p*32;
      *(uint4*)&As[row*72 + kc] =
          *(const uint4*)(Abf + (size_t)(bm*128 + row)*CIN + ks*64 + kc);
      *(uint4*)&Bs[row*72 + kc] =
          *(const uint4*)(Wcb + (size_t)(bn*128 + row)*CIN + ks*64 + kc);
    }
    __syncthreads();
    #pragma unroll
    for (int kk = 0; kk < 2; ++kk) {
      bf16x8 af[4], bfr[4];
      #pragma unroll
      for (int mt = 0; mt < 4; ++mt)
        af[mt] = *(const bf16x8*)&As[(wm*64 + mt*16 + l15)*72 + kk*32 + q*8];
      #pragma unroll
      for (int nt = 0; nt < 4; ++nt)
        bfr[nt] = *(const bf16x8*)&Bs[(wn*64 + nt*16 + l15)*72 + kk*32 + q*8];
      #pragma unroll
      for (int mt = 0; mt < 4; ++mt)
        #pragma unroll
        for (int nt = 0; nt < 4; ++nt)
          acc[mt][nt] = __builtin_amdgcn_mfma_f32_16x16x32_bf16(af[mt], bfr[nt], acc[mt][nt], 0, 0, 0);
    }
    __syncthreads();
  }
  #pragma unroll
  for (int nt = 0; nt < 4; ++nt) {
    const int j = bn*128 + wn*64 + nt*16 + l15;    // 0..639, 16-aligned groups
    const float bv = bgc[j];
    #pragma unroll
    for (int mt = 0; mt < 4; ++mt) {
      const int m0 = bm*128 + wm*64 + mt*16 + q*4;
      #pragma unroll
      for (int r = 0; r < 4; ++r) {
        const int n = m0 + r;
        const float v = 1.0f / (1.0f + __expf(-(acc[mt][nt][r] + bv)));
        if (j < 64)       gm1[n*FEAT + j]        = v;
        else if (j < 320) gm2[n*CIN  + (j-64)]   = v;
        else if (j < 384) gs1[n*FEAT + (j-320)]  = v;
        else              gs2[n*OUTC + (j-384)]  = v;
      }
    }
  }
}

// ---------------------------------------------------------------------------
// Dyn GEMM: params = pf @ W_dyn + b_dyn, bf16 MFMA 16x16x32.
// M=1024, K=256, N=32768. Block tile 128x128, BK=64, 4 waves each 64x64.
// Writes p_in / p_out directly into d_out regions.
// ---------------------------------------------------------------------------
__global__ __launch_bounds__(256) void k_dyn(
    const unsigned short* __restrict__ Abf, const unsigned short* __restrict__ Bt,
    const float* __restrict__ bias, float* __restrict__ out)
{
  const int bn = blockIdx.x;   // 0..255
  const int bm = blockIdx.y;   // 0..7
  __shared__ short As[128*72];
  __shared__ short Bs[128*72];
  const int t = threadIdx.x;
  const int wave = t >> 6, lane = t & 63;
  const int q = lane >> 4, l15 = lane & 15;
  const int wm = wave >> 1, wn = wave & 1;
  floatx4 acc[4][4];
  #pragma unroll
  for (int mt=0;mt<4;++mt)
    #pragma unroll
    for (int nt=0;nt<4;++nt)
      #pragma unroll
      for (int r=0;r<4;++r) acc[mt][nt][r] = 0.f;

  const int r0 = t >> 3;
  const int kc = (t & 7) * 8;

  for (int ks = 0; ks < 4; ++ks) {
    #pragma unroll
    for (int p = 0; p < 4; ++p) {
      const int row = r0 + p*32;
      *(uint4*)&As[row*72 + kc] =
          *(const uint4*)(Abf + (size_t)(bm*128 + row)*CIN + ks*64 + kc);
      *(uint4*)&Bs[row*72 + kc] =
          *(const uint4*)(Bt  + (size_t)(bn*128 + row)*CIN + ks*64 + kc);
    }
    __syncthreads();
    #pragma unroll
    for (int kk = 0; kk < 2; ++kk) {
      bf16x8 af[4], bfr[4];
      #pragma unroll
      for (int mt = 0; mt < 4; ++mt)
        af[mt] = *(const bf16x8*)&As[(wm*64 + mt*16 + l15)*72 + kk*32 + q*8];
      #pragma unroll
      for (int nt = 0; nt < 4; ++nt)
        bfr[nt] = *(const bf16x8*)&Bs[(wn*64 + nt*16 + l15)*72 + kk*32 + q*8];
      #pragma unroll
      for (int mt = 0; mt < 4; ++mt)
        #pragma unroll
        for (int nt = 0; nt < 4; ++nt)
          acc[mt][nt] = __builtin_amdgcn_mfma_f32_16x16x32_bf16(af[mt], bfr[nt], acc[mt][nt], 0, 0, 0);
    }
    __syncthreads();
  }
  #pragma unroll
  for (int nt = 0; nt < 4; ++nt) {
    const int j = bn*128 + wn*64 + nt*16 + l15;
    const float bv = bias[j];
    float* base; int jj;
    if (j < CF) { base = out + 262144;            jj = j;      }
    else        { base = out + 262144 + 16777216; jj = j - CF; }
    #pragma unroll
    for (int mt = 0; mt < 4; ++mt) {
      const int m0 = bm*128 + wm*64 + mt*16 + q*4;
      #pragma unroll
      for (int r = 0; r < 4; ++r)
        base[(size_t)(m0 + r)*CF + jj] = acc[mt][nt][r] + bv;
    }
  }
}

// ---------------------------------------------------------------------------
// k_inout: fused per-n  t = relu(ln(x @ u_in)) ; f = relu(ln(t @ u_out)).
// t lives entirely in LDS (ts2 [f][h]) — no tbuf round-trip.
// Phase A: lane = f (LN over F=64 = lane dim). Phase B: lane+3 chunks = o,
// LN over OUT=256. u chunks built on the fly from gates + pre + p.
// LDS: us 32KB (shared A/B) + xs 26.8KB (A only) + ts2 13.4KB + gates 2.5KB
//    = 75 KB -> 2 blocks/CU.
// ---------------------------------------------------------------------------
__global__ __launch_bounds__(256) void k_inout(
    const float* __restrict__ infeat,
    const float* __restrict__ preI3, const float* __restrict__ pin,
    const float* __restrict__ preO3, const float* __restrict__ pout,
    const float* __restrict__ gm1, const float* __restrict__ gm2,
    const float* __restrict__ gs1, const float* __restrict__ gs2,
    const float* __restrict__ gin, const float* __restrict__ bin,
    const float* __restrict__ gout, const float* __restrict__ bout,
    unsigned short* __restrict__ fbuf)
{
  const int n = blockIdx.x;
  const int t = threadIdx.x;
  const int wave = t >> 6, lane = t & 63;
  __shared__ float us[8192];          // phase A: u_in [128c][64f]; phase B: u_out [32f][256o]
  __shared__ float xs[128*52 + 16];   // phase A x chunk [c][h], pad 49->52
  __shared__ float ts2[64*52 + 16];   // t transposed [f][h]
  __shared__ float m1s[64], s1s[64];
  __shared__ float m2s[256], s2s[256];
  if (t < 64) { m1s[t] = gm1[n*64 + t]; s1s[t] = gs1[n*64 + t]; }
  m2s[t] = gm2[n*256 + t];
  s2s[t] = gs2[n*256 + t];

  // ---------------- phase A: t = relu(ln(x @ u_in)) ----------------
  {
    float acc[16];
    #pragma unroll
    for (int i = 0; i < 16; ++i) acc[i] = 0.f;

    for (int cc = 0; cc < 2; ++cc) {
      __syncthreads();
      for (int i = t; i < 128*49; i += 256) {
        const int c = i / 49, h = i - c*49;
        xs[c*52 + h] = infeat[(size_t)n*12544 + (size_t)(cc*128 + c)*49 + h];
      }
      for (int i = t*4; i < 8192; i += 1024) {
        const int gi = cc*8192 + i;
        const float4 pr = *(const float4*)(preI3 + (size_t)n*16384 + gi);
        const float4 pp = *(const float4*)(pin   + (size_t)n*16384 + gi);
        const int c = gi >> 6, f0 = gi & 63;
        const float m2v = m2s[c];
        float4 w;
        { const float m1v = m1s[f0+0]; const float ui = m1v*pr.x + (1.f-m1v)*pp.x; w.x = m2v*ui + (1.f-m2v)*pp.x; }
        { const float m1v = m1s[f0+1]; const float ui = m1v*pr.y + (1.f-m1v)*pp.y; w.y = m2v*ui + (1.f-m2v)*pp.y; }
        { const float m1v = m1s[f0+2]; const float ui = m1v*pr.z + (1.f-m1v)*pp.z; w.z = m2v*ui + (1.f-m2v)*pp.z; }
        { const float m1v = m1s[f0+3]; const float ui = m1v*pr.w + (1.f-m1v)*pp.w; w.w = m2v*ui + (1.f-m2v)*pp.w; }
        *(float4*)&us[i] = w;
      }
      __syncthreads();
      #pragma unroll
      for (int p = 0; p < 2; ++p) {
        const int hbase = p*32 + wave*8;
        float* accp = &acc[p*8];
        for (int c = 0; c < 128; ++c) {
          const float uv = us[c*64 + lane];
          const float4 xa = *(const float4*)&xs[c*52 + hbase];
          const float4 xb = *(const float4*)&xs[c*52 + hbase + 4];
          accp[0] += uv*xa.x; accp[1] += uv*xa.y; accp[2] += uv*xa.z; accp[3] += uv*xa.w;
          accp[4] += uv*xb.x; accp[5] += uv*xb.y; accp[6] += uv*xb.z; accp[7] += uv*xb.w;
        }
      }
    }
    const float gv = gin[lane], bv = bin[lane];
    #pragma unroll
    for (int p = 0; p < 2; ++p) {
      const int hbase = p*32 + wave*8;
      #pragma unroll
      for (int j = 0; j < 8; ++j) {
        const int h = hbase + j;
        if (h >= 49) break;                 // wave-uniform
        const float v = acc[p*8+j];
        float s1 = v, s2 = v*v;
        #pragma unroll
        for (int off = 32; off > 0; off >>= 1) {
          s1 += __shfl_xor(s1, off);
          s2 += __shfl_xor(s2, off);
        }
        const float mean = s1 * (1.f/64.f);
        const float var  = s2 * (1.f/64.f) - mean*mean;
        const float rs   = rsqrtf(var + 1e-5f);
        const float o    = (v - mean)*rs*gv + bv;
        ts2[lane*52 + h] = fmaxf(o, 0.f);    // t[f=lane][h]
      }
    }
  }

  // ---------------- phase B: f = relu(ln(t @ u_out)) ----------------
  float acc2[2][8][4];
  #pragma unroll
  for (int p=0;p<2;++p)
    #pragma unroll
    for (int j=0;j<8;++j)
      #pragma unroll
      for (int k=0;k<4;++k) acc2[p][j][k] = 0.f;

  for (int fc_ = 0; fc_ < 2; ++fc_) {
    __syncthreads();     // orders ts2 writes (1st iter) and frees us (both)
    for (int i = t*4; i < 8192; i += 1024) {
      const int gi = fc_*8192 + i;
      const float4 pr = *(const float4*)(preO3 + (size_t)n*16384 + gi);
      const float4 pp = *(const float4*)(pout  + (size_t)n*16384 + gi);
      const int f = gi >> 8, o0 = gi & 255;
      const float s1v = s1s[f];
      float4 w;
      { const float s2v = s2s[o0+0]; const float uo = s1v*pr.x + (1.f-s1v)*pp.x; w.x = s2v*uo + (1.f-s2v)*pp.x; }
      { const float s2v = s2s[o0+1]; const float uo = s1v*pr.y + (1.f-s1v)*pp.y; w.y = s2v*uo + (1.f-s2v)*pp.y; }
      { const float s2v = s2s[o0+2]; const float uo = s1v*pr.z + (1.f-s1v)*pp.z; w.z = s2v*uo + (1.f-s2v)*pp.z; }
      { const float s2v = s2s[o0+3]; const float uo = s1v*pr.w + (1.f-s1v)*pp.w; w.w = s2v*uo + (1.f-s2v)*pp.w; }
      *(float4*)&us[i] = w;
    }
    __syncthreads();
    #pragma unroll
    for (int p = 0; p < 2; ++p) {
      const int hbase = (p*4 + wave)*8;
      for (int fl = 0; fl < 32; ++fl) {
        const float u0 = us[fl*256 + lane];
        const float u1 = us[fl*256 + lane + 64];
        const float u2v= us[fl*256 + lane + 128];
        const float u3 = us[fl*256 + lane + 192];
        const int f = fc_*32 + fl;
        const float4 ta = *(const float4*)&ts2[f*52 + hbase];
        const float4 tb = *(const float4*)&ts2[f*52 + hbase + 4];
        const float tv[8] = {ta.x,ta.y,ta.z,ta.w,tb.x,tb.y,tb.z,tb.w};
        #pragma unroll
        for (int j = 0; j < 8; ++j) {
          acc2[p][j][0] += tv[j]*u0;
          acc2[p][j][1] += tv[j]*u1;
          acc2[p][j][2] += tv[j]*u2v;
          acc2[p][j][3] += tv[j]*u3;
        }
      }
    }
  }
  const float go0=gout[lane], go1=gout[lane+64], go2=gout[lane+128], go3=gout[lane+192];
  const float bo0=bout[lane], bo1=bout[lane+64], bo2=bout[lane+128], bo3=bout[lane+192];
  #pragma unroll
  for (int p = 0; p < 2; ++p) {
    const int hbase = (p*4 + wave)*8;
    #pragma unroll
    for (int j = 0; j < 8; ++j) {
      const int h = hbase + j;
      if (h >= 49) break;                 // wave-uniform
      const float v0 = acc2[p][j][0], v1 = acc2[p][j][1], v2 = acc2[p][j][2], v3 = acc2[p][j][3];
      float s1 = v0+v1+v2+v3;
      float s2 = v0*v0+v1*v1+v2*v2+v3*v3;
      #pragma unroll
      for (int off = 32; off > 0; off >>= 1) {
        s1 += __shfl_xor(s1, off);
        s2 += __shfl_xor(s2, off);
      }
      const float mean = s1 * (1.f/256.f);
      const float var  = s2 * (1.f/256.f) - mean*mean;
      const float rs   = rsqrtf(var + 1e-5f);
      unsigned short* dst = fbuf + (size_t)(n*49 + h)*256;
      dst[lane      ] = f2bfu(fmaxf((v0-mean)*rs*go0 + bo0, 0.f));
      dst[lane + 64 ] = f2bfu(fmaxf((v1-mean)*rs*go1 + bo1, 0.f));
      dst[lane + 128] = f2bfu(fmaxf((v2-mean)*rs*go2 + bo2, 0.f));
      dst[lane + 192] = f2bfu(fmaxf((v3-mean)*rs*go3 + bo3, 0.f));
    }
  }
}

// ---------------------------------------------------------------------------
// fc GEMM: partial[bk] = f_bf16[64 rows] @ Wfc_t chunk. bf16 MFMA.
// Grid (16 bm, 2 bn, 14 bk); chunk K = 896 = 14 * 64.
// ---------------------------------------------------------------------------
__global__ __launch_bounds__(256) void k_fc(
    const unsigned short* __restrict__ Abf, const unsigned short* __restrict__ Bbf,
    float* __restrict__ part)
{
  const int bm = blockIdx.x, bn = blockIdx.y, bk = blockIdx.z;
  __shared__ short As[64*72];
  __shared__ short Bs[128*72];
  const int t = threadIdx.x;
  const int wave = t >> 6, lane = t & 63;
  const int q = lane >> 4, l15 = lane & 15;
  floatx4 acc[4][2];
  #pragma unroll
  for (int mt=0;mt<4;++mt)
    #pragma unroll
    for (int nt=0;nt<2;++nt)
      #pragma unroll
      for (int r=0;r<4;++r) acc[mt][nt][r] = 0.f;

  for (int ks = 0; ks < 14; ++ks) {
    const int k0 = bk*896 + ks*64;
    {
      int row = t >> 3; const int kc = (t & 7) * 8;
      #pragma unroll
      for (int p2 = 0; p2 < 2; ++p2, row += 32) {
        const uint4 v = *(const uint4*)(Abf + (size_t)(bm*64 + row)*KFC + k0 + kc);
        *(uint4*)&As[row*72 + kc] = v;
      }
    }
    {
      int col = t >> 3; const int kc = (t & 7) * 8;
      #pragma unroll
      for (int p2 = 0; p2 < 4; ++p2, col += 32) {
        const uint4 v = *(const uint4*)(Bbf + (size_t)(bn*128 + col)*KFC + k0 + kc);
        *(uint4*)&Bs[col*72 + kc] = v;
      }
    }
    __syncthreads();
    #pragma unroll
    for (int kk = 0; kk < 2; ++kk) {
      bf16x8 af[4], bfr[2];
      #pragma unroll
      for (int mt = 0; mt < 4; ++mt)
        af[mt] = *(const bf16x8*)&As[(mt*16 + l15)*72 + kk*32 + q*8];
      #pragma unroll
      for (int nt = 0; nt < 2; ++nt)
        bfr[nt] = *(const bf16x8*)&Bs[(wave*32 + nt*16 + l15)*72 + kk*32 + q*8];
      #pragma unroll
      for (int mt = 0; mt < 4; ++mt)
        #pragma unroll
        for (int nt = 0; nt < 2; ++nt)
          acc[mt][nt] = __builtin_amdgcn_mfma_f32_16x16x32_bf16(af[mt], bfr[nt], acc[mt][nt], 0, 0, 0);
    }
    __syncthreads();
  }
  float* dst = part + (size_t)bk*NPROP*OUTC;
  #pragma unroll
  for (int mt = 0; mt < 4; ++mt)
    #pragma unroll
    for (int nt = 0; nt < 2; ++nt) {
      const int o  = bn*128 + wave*32 + nt*16 + l15;
      const int m0 = bm*64 + mt*16 + q*4;
      #pragma unroll
      for (int r = 0; r < 4; ++r)
        dst[(size_t)(m0 + r)*OUTC + o] = acc[mt][nt][r];
    }
}

// ---------------------------------------------------------------------------
// fc reduce: sum 14 partials + b_fc, LN(g_fcn,b_fcn), relu -> out[0:262144]
// ---------------------------------------------------------------------------
__global__ __launch_bounds__(256) void k_fcred(
    const float* __restrict__ part, const float* __restrict__ bfc,
    const float* __restrict__ gn, const float* __restrict__ bnm,
    float* __restrict__ out0)
{
  const int n = blockIdx.x, t = threadIdx.x;
  float acc = bfc[t];
  #pragma unroll
  for (int s = 0; s < 14; ++s) acc += part[(size_t)s*NPROP*OUTC + n*256 + t];
  __shared__ float red[8];
  float s1 = acc, s2 = acc*acc;
  #pragma unroll
  for (int off = 32; off > 0; off >>= 1) {
    s1 += __shfl_xor(s1, off);
    s2 += __shfl_xor(s2, off);
  }
  const int wave = t >> 6, lane = t & 63;
  if (lane == 0) { red[wave] = s1; red[4+wave] = s2; }
  __syncthreads();
  const float S1 = red[0]+red[1]+red[2]+red[3];
  const float S2 = red[4]+red[5]+red[6]+red[7];
  const float mean = S1 * (1.f/256.f);
  const float var  = S2 * (1.f/256.f) - mean*mean;
  const float rs   = rsqrtf(var + 1e-5f);
  const float v = (acc - mean)*rs*gn[t] + bnm[t];
  out0[n*256 + t] = fmaxf(v, 0.f);
}

// ---------------------------------------------------------------------------
extern "C" void kernel_launch(void* const* d_in, const int* in_sizes, int n_in,
                              void* d_out, int out_size, void* d_ws, size_t ws_size,
                              hipStream_t stream)
{
  const float* pf    = (const float*)d_in[0];
  const float* infe  = (const float*)d_in[1];
  const float* preI  = (const float*)d_in[2];
  const float* preO  = (const float*)d_in[3];
  const float* Wdyn  = (const float*)d_in[4];
  const float* bdyn  = (const float*)d_in[5];
  const float* g_in  = (const float*)d_in[6];
  const float* b_in  = (const float*)d_in[7];
  const float* g_out = (const float*)d_in[8];
  const float* b_out = (const float*)d_in[9];
  const float* Wfc   = (const float*)d_in[10];
  const float* bfc   = (const float*)d_in[11];
  const float* gfcn  = (const float*)d_in[12];
  const float* bfcn  = (const float*)d_in[13];
  const float* WM1   = (const float*)d_in[14];
  const float* bM1   = (const float*)d_in[15];
  const float* WM2   = (const float*)d_in[16];
  const float* bM2   = (const float*)d_in[17];
  const float* WS1   = (const float*)d_in[18];
  const float* bS1   = (const float*)d_in[19];
  const float* WS2   = (const float*)d_in[20];
  const float* bS2   = (const float*)d_in[21];

  // ws layout (bytes), flat:
  //        0 gm1    262144
  //   262144 gm2    1048576
  //  1310720 gs1    262144
  //  1572864 gs2    1048576
  //  2621440 wdynt  16777216  (bf16)
  // 19398656 wfct   6422528   (bf16)
  // 25821184 abf    524288    (bf16)
  // 26345472 wgcb   327680    (bf16)
  // 26673152 bgc    2560
  // 26677248 part   14680064
  // 41357312 fbuf   25690112  (bf16)   total 67047424 B (~64 MB)
  char* wsb = (char*)d_ws;
  float* gm1  = (float*)(wsb + 0);
  float* gm2  = (float*)(wsb + 262144);
  float* gs1  = (float*)(wsb + 1310720);
  float* gs2  = (float*)(wsb + 1572864);
  unsigned short* wdynt = (unsigned short*)(wsb + 2621440);
  unsigned short* wfct  = (unsigned short*)(wsb + 19398656);
  unsigned short* abf   = (unsigned short*)(wsb + 25821184);
  unsigned short* wgcb  = (unsigned short*)(wsb + 26345472);
  float* bgc  = (float*)(wsb + 26673152);
  float* part = (float*)(wsb + 26677248);
  unsigned short* fbuf  = (unsigned short*)(wsb + 41357312);

  const float* pre_in3  = preI + (size_t)3*NPROP*CIN*FEAT;
  const float* pre_out3 = preO + (size_t)3*NPROP*FEAT*OUTC;
  const float* p_in  = (const float*)d_out + 262144;
  const float* p_out = (const float*)d_out + 262144 + 16777216;
  float* out0 = (float*)d_out;

  k_prep  <<<dim3(3728),     256, 0, stream>>>(Wdyn, wdynt, Wfc, wfct, pf, abf,
                                               WM1, WM2, WS1, WS2,
                                               bM1, bM2, bS1, bS2, wgcb, bgc);
  k_gatesM<<<dim3(5, 8),     256, 0, stream>>>(abf, wgcb, bgc, gm1, gm2, gs1, gs2);
  k_dyn   <<<dim3(256, 8),   256, 0, stream>>>(abf, wdynt, bdyn, (float*)d_out);
  k_inout <<<dim3(1024),     256, 0, stream>>>(infe, pre_in3, p_in, pre_out3, p_out,
                                               gm1, gm2, gs1, gs2,
                                               g_in, b_in, g_out, b_out, fbuf);
  k_fc    <<<dim3(16, 2, 14),256, 0, stream>>>(fbuf, wfct, part);
  k_fcred <<<dim3(1024),     256, 0, stream>>>(part, bfc, gfcn, bfcn, out0);
}